// Round 5
// baseline (264.518 us; speedup 1.0000x reference)
//
#include <hip/hip_runtime.h>
#include <hip/hip_bf16.h>
#include <math.h>

// Fused GQA attention, MI355X/gfx950.
// B=2 S=2048 E=2048 H=16 G=4 D=128, causal, fp32 in/out, bf16 MFMA compute.
//
//   1. conv_x      : x fp32 -> bf16 [4096][2048]
//   2. transpose_w : Wq/Wk/Wv [nh][E][128] fp32 -> Wt [3072][2048] bf16 (B^T layout)
//   3. build_bias  : bq|bk|bv -> bc[3072] fp32
//   4. qkv_gemm    : bf16 MFMA GEMM (128^2 tile, BK=32, global_load_lds dbuf),
//                    flat grid 768 + XCD swizzle (T1). Epilogue: +bias, Q pre-scaled,
//                    Q/K [bh][s][128], V transposed [bg][128][s].
//   5. attn (v3)   : flash attention. 512 blocks x 4 waves, QBLK=64, pair-balanced
//                    (block pair j,31-j => 33 tiles each), 2 blocks/CU (64KB LDS).
//                    XCD swizzle: each XCD owns one (b,g) => KV fits 4MB XCD L2.
//                    KV dbuf staged via global_load_lds, XOR-swizzled through
//                    pre-swizzled global source. Swapped QK^T keeps softmax
//                    lane-local; PV uses permuted-k assignment
//                    R(grp*8+j)=16*(j>>2)+4*grp+(j&3) so the P fragment is
//                    ALREADY lane-local (no LDS/shuffle); V frags = 2x ds_read_b64
//                    assembled via union. LDS buffer pointers computed
//                    arithmetically (no pointer arrays - addrspacecast init is
//                    unsupported). Defer-max (THR=8), setprio around MFMA.

typedef __attribute__((ext_vector_type(8))) short bf16x8;
typedef __attribute__((ext_vector_type(4))) short s16x4;
typedef __attribute__((ext_vector_type(4))) float f32x4;

union v8u { bf16x8 v8; s16x4 half[2]; };

#define LOG2E 1.4426950408889634f

__device__ __forceinline__ short f2bf(float f) {
  union { float f; unsigned u; } v; v.f = f;
  unsigned r = v.u + 0x7FFFu + ((v.u >> 16) & 1u);
  return (short)(r >> 16);
}

__device__ __forceinline__ short hwbf(float f) {
  __hip_bfloat16 h = __float2bfloat16(f);
  return *(short*)&h;
}

__device__ __forceinline__ void async16(const void* g, void* l) {
  __builtin_amdgcn_global_load_lds(
      (const __attribute__((address_space(1))) void*)g,
      (__attribute__((address_space(3))) void*)l, 16, 0, 0);
}

__device__ __forceinline__ f32x4 mfma16(bf16x8 a, bf16x8 b, f32x4 c) {
  return __builtin_amdgcn_mfma_f32_16x16x32_bf16(a, b, c, 0, 0, 0);
}

// ---------------------------------------------------------------- prep kernels

__global__ void conv_x(const float4* __restrict__ x, s16x4* __restrict__ xb) {
  const int i = blockIdx.x * 256 + threadIdx.x;
  float4 v = x[i];
  s16x4 o;
  o[0] = f2bf(v.x); o[1] = f2bf(v.y); o[2] = f2bf(v.z); o[3] = f2bf(v.w);
  xb[i] = o;
}

__global__ void transpose_w(const float* __restrict__ src, short* __restrict__ wt, int c0) {
  __shared__ float t[32][33];
  const int hh = blockIdx.z;
  const int e0 = blockIdx.x * 32, d0 = blockIdx.y * 32;
  const int tx = threadIdx.x, ty = threadIdx.y;  // (32, 8)
  const float* s = src + (size_t)hh * 2048 * 128;
#pragma unroll
  for (int i = ty; i < 32; i += 8)
    t[i][tx] = s[(size_t)(e0 + i) * 128 + d0 + tx];
  __syncthreads();
#pragma unroll
  for (int i = ty; i < 32; i += 8)
    wt[(size_t)(c0 + hh * 128 + d0 + i) * 2048 + e0 + tx] = f2bf(t[tx][i]);
}

__global__ void build_bias(const float* __restrict__ bq, const float* __restrict__ bk,
                           const float* __restrict__ bv, float* __restrict__ bc) {
  const int c = blockIdx.x * 256 + threadIdx.x;
  float v;
  if (c < 2048)      v = bq[c];
  else if (c < 2560) v = bk[c - 2048];
  else               v = bv[c - 2560];
  bc[c] = v;
}

// ---------------------------------------------------------------- QKV GEMM

__global__ __launch_bounds__(256) void qkv_gemm(
    const short* __restrict__ xb, const short* __restrict__ wt,
    const float* __restrict__ bc,
    short* __restrict__ qb, short* __restrict__ kb, short* __restrict__ vt)
{
  constexpr int E = 2048, BK = 32;
  __shared__ short Al[2][128 * BK];
  __shared__ short Bl[2][128 * BK];
  const int tid = threadIdx.x;
  const int lane = tid & 63, wave = tid >> 6;
  const int wr = wave >> 1, wc = wave & 1;
  const int l16 = lane & 15, grp = lane >> 4;
  // T1 XCD swizzle: 768 blocks, 96 contiguous works per XCD (4 m-rows x all n).
  const int work = (blockIdx.x & 7) * 96 + (blockIdx.x >> 3);
  const int m0 = (work / 24) * 128, n0 = (work % 24) * 128;

  const int c1 = tid, c2 = tid + 256;
  const int r1 = c1 >> 2, s1 = c1 & 3, r2 = c2 >> 2, s2 = c2 & 3;

  f32x4 acc[4][4] = {};

  async16(xb + (size_t)(m0 + r1) * E + s1 * 8, (char*)Al[0] + c1 * 16);
  async16(xb + (size_t)(m0 + r2) * E + s2 * 8, (char*)Al[0] + c2 * 16);
  async16(wt + (size_t)(n0 + r1) * E + s1 * 8, (char*)Bl[0] + c1 * 16);
  async16(wt + (size_t)(n0 + r2) * E + s2 * 8, (char*)Bl[0] + c2 * 16);
  __syncthreads();

  const int nk = E / BK;  // 64
  for (int t = 0; t < nk; ++t) {
    const int cur = t & 1;
    if (t + 1 < nk) {
      const int k0 = (t + 1) * BK;
      async16(xb + (size_t)(m0 + r1) * E + k0 + s1 * 8, (char*)Al[cur ^ 1] + c1 * 16);
      async16(xb + (size_t)(m0 + r2) * E + k0 + s2 * 8, (char*)Al[cur ^ 1] + c2 * 16);
      async16(wt + (size_t)(n0 + r1) * E + k0 + s1 * 8, (char*)Bl[cur ^ 1] + c1 * 16);
      async16(wt + (size_t)(n0 + r2) * E + k0 + s2 * 8, (char*)Bl[cur ^ 1] + c2 * 16);
    }
    bf16x8 af[4], bfr[4];
#pragma unroll
    for (int mi = 0; mi < 4; ++mi)
      af[mi] = *(const bf16x8*)&Al[cur][(wr * 64 + mi * 16 + l16) * BK + grp * 8];
#pragma unroll
    for (int ni = 0; ni < 4; ++ni)
      bfr[ni] = *(const bf16x8*)&Bl[cur][(wc * 64 + ni * 16 + l16) * BK + grp * 8];
#pragma unroll
    for (int mi = 0; mi < 4; ++mi)
#pragma unroll
      for (int ni = 0; ni < 4; ++ni)
        acc[mi][ni] = mfma16(af[mi], bfr[ni], acc[mi][ni]);
    __syncthreads();
  }

  const float qscale = 0.08838834764831845f;  // 1/sqrt(128)
#pragma unroll
  for (int ni = 0; ni < 4; ++ni) {
    const int c = n0 + wc * 64 + ni * 16 + l16;
    const float bias = bc[c];
    const int d = c & 127;
#pragma unroll
    for (int mi = 0; mi < 4; ++mi) {
      const int rbase = m0 + wr * 64 + mi * 16 + grp * 4;
      const int b = rbase >> 11;
      const int s = rbase & 2047;
      f32x4 a = acc[mi][ni];
      if (c < 2048) {
        const int h = c >> 7;
        short* dst = qb + ((size_t)(b * 16 + h) * 2048 + s) * 128 + d;
#pragma unroll
        for (int r = 0; r < 4; ++r) dst[(size_t)r * 128] = f2bf((a[r] + bias) * qscale);
      } else if (c < 2560) {
        const int gi = (c >> 7) & 3;
        short* dst = kb + ((size_t)(b * 4 + gi) * 2048 + s) * 128 + d;
#pragma unroll
        for (int r = 0; r < 4; ++r) dst[(size_t)r * 128] = f2bf(a[r] + bias);
      } else {
        const int gi = (c >> 7) & 3;
        s16x4 pk;
#pragma unroll
        for (int r = 0; r < 4; ++r) pk[r] = f2bf(a[r] + bias);
        *(s16x4*)&vt[((size_t)(b * 4 + gi) * 128 + d) * 2048 + s] = pk;
      }
    }
  }
}

// ---------------------------------------------------------------- attention v3

// Stage K tile [64][128]bf16 (256B rows) and V^T tile [128][64]bf16 (128B rows).
// 256 threads: 4 x 16B chunks each per tile. XOR-swizzle via global source.
__device__ __forceinline__ void stageKV(char* kd, char* vd,
                                        const short* __restrict__ Kg,
                                        const short* __restrict__ Vg,
                                        int kv0, int tid) {
#pragma unroll
  for (int rd = 0; rd < 4; ++rd) {
    const int off = rd * 4096 + tid * 16;
    const int row = off >> 8, colb = off & 255;
    const int sc = colb ^ ((row & 7) << 4);
    async16(Kg + (size_t)(kv0 + row) * 128 + (sc >> 1), kd + off);
  }
#pragma unroll
  for (int rd = 0; rd < 4; ++rd) {
    const int off = rd * 4096 + tid * 16;
    const int row = off >> 7, colb = off & 127;
    const int sc = colb ^ ((row & 7) << 4);
    async16(Vg + (size_t)row * 2048 + kv0 + (sc >> 1), vd + off);
  }
}

__global__ __launch_bounds__(256) void attn(
    const short* __restrict__ qb, const short* __restrict__ kb,
    const short* __restrict__ vt, float* __restrict__ out)
{
  constexpr int S = 2048, D = 128;
  extern __shared__ char lds[];
  const int tid = threadIdx.x;
  const int lane = tid & 63, wave = tid >> 6;
  const int l16 = lane & 15, grp = lane >> 4;
  // XCD swizzle: 512 blocks; XCD c owns (b,g)=c (KV 1MB fits 4MB XCD L2).
  const int work = (blockIdx.x & 7) * 64 + (blockIdx.x >> 3);
  const int bg = work >> 6, s6 = work & 63;
  const int b = bg >> 2, g = bg & 3;
  const int h = g * 4 + (s6 >> 4);
  const int x = s6 & 15;  // pair index: phases {x, 31-x}

  const short* Qg = qb + (size_t)(b * 16 + h) * S * D;
  const short* Kg = kb + (size_t)(b * 4 + g) * S * D;
  const short* Vg = vt + (size_t)(b * 4 + g) * (size_t)D * S;
  const int swz = (l16 & 7) << 4;

#pragma unroll
  for (int p = 0; p < 2; ++p) {
    const int jj = p ? (31 - x) : x;
    const int q0 = jj * 64 + wave * 16;
    const int nt = jj + 1;

    bf16x8 qf[4];
#pragma unroll
    for (int c = 0; c < 4; ++c)
      qf[c] = *(const bf16x8*)&Qg[(size_t)(q0 + l16) * D + c * 32 + grp * 8];

    f32x4 o[8] = {};
    float mrun = -INFINITY, lrun = 0.f;

    stageKV(lds, lds + 32768, Kg, Vg, 0, tid);
    __syncthreads();

    for (int t = 0; t < nt; ++t) {
      const int kv0 = t << 6;
      const int cur = t & 1;
      if (t + 1 < nt)
        stageKV(lds + (cur ^ 1) * 16384, lds + 32768 + (cur ^ 1) * 16384,
                Kg, Vg, kv0 + 64, tid);
      char* const Kb = lds + cur * 16384;
      char* const Vb = lds + 32768 + cur * 16384;

      // ---- QK^T: ST[k][q], k = f*16+grp*4+r, q = l16
      f32x4 st[4] = {};
      __builtin_amdgcn_s_setprio(1);
#pragma unroll
      for (int c = 0; c < 4; ++c)
#pragma unroll
        for (int f = 0; f < 4; ++f) {
          const int row = f * 16 + l16;
          bf16x8 kf = *(const bf16x8*)(Kb + row * 256 + ((c * 64 + grp * 16) ^ swz));
          st[f] = mfma16(kf, qf[c], st[f]);
        }
      __builtin_amdgcn_s_setprio(0);
      if (t == nt - 1) {  // diagonal tile: causal mask
        const int qa = q0 + l16;
#pragma unroll
        for (int f = 0; f < 4; ++f)
#pragma unroll
          for (int r = 0; r < 4; ++r)
            if (kv0 + f * 16 + grp * 4 + r > qa) st[f][r] = -INFINITY;
      }
      // ---- online softmax, defer-max (THR=8)
      float tmax = -INFINITY;
#pragma unroll
      for (int f = 0; f < 4; ++f)
#pragma unroll
        for (int r = 0; r < 4; ++r) tmax = fmaxf(tmax, st[f][r]);
      tmax = fmaxf(tmax, __shfl_xor(tmax, 16));
      tmax = fmaxf(tmax, __shfl_xor(tmax, 32));
      float fac = 1.0f;
      if (!__all(tmax <= mrun + 8.0f)) {
        const float mn = fmaxf(mrun, tmax);
        fac = exp2f((mrun - mn) * LOG2E);
#pragma unroll
        for (int f8 = 0; f8 < 8; ++f8) o[f8] *= fac;
        mrun = mn;
      }
      float lsum = 0.f;
      float ps[16];
#pragma unroll
      for (int f = 0; f < 4; ++f)
#pragma unroll
        for (int r = 0; r < 4; ++r) {
          const float pv = exp2f((st[f][r] - mrun) * LOG2E);
          ps[f * 4 + r] = pv;
          lsum += pv;
        }
      lsum += __shfl_xor(lsum, 16);
      lsum += __shfl_xor(lsum, 32);
      lrun = lrun * fac + lsum;

      // ---- P pack: permuted-k PV => P fragment is already lane-local.
      // MFMA_a covers k = R(grp*8+j) = 16*(j>>2)+4*grp+(j&3)  -> ps[0..7]
      // MFMA_b covers k = 32 + same                            -> ps[8..15]
      bf16x8 pba, pbb;
#pragma unroll
      for (int i = 0; i < 8; ++i) { pba[i] = hwbf(ps[i]); pbb[i] = hwbf(ps[8 + i]); }

      // ---- PV: O^T[d][q] += V^T * P ; V frags = 2x ds_read_b64 per MFMA,
      // assembled via union (vector elements are not addressable).
      __builtin_amdgcn_s_setprio(1);
#pragma unroll
      for (int f8 = 0; f8 < 8; ++f8) {
        const char* vrow = Vb + (f8 * 16 + l16) * 128;
        v8u va, vb2;
        va.half[0]  = *(const s16x4*)(vrow + ((grp * 8) ^ swz));
        va.half[1]  = *(const s16x4*)(vrow + ((32 + grp * 8) ^ swz));
        o[f8] = mfma16(va.v8, pba, o[f8]);
        vb2.half[0] = *(const s16x4*)(vrow + ((64 + grp * 8) ^ swz));
        vb2.half[1] = *(const s16x4*)(vrow + ((96 + grp * 8) ^ swz));
        o[f8] = mfma16(vb2.v8, pbb, o[f8]);
      }
      __builtin_amdgcn_s_setprio(0);
      __syncthreads();  // stage(t+1) drained + reads of cur done
    }

    const float inv = 1.f / lrun;
    float* orow = out + ((size_t)b * S + q0 + l16) * 2048 + h * D;
#pragma unroll
    for (int f8 = 0; f8 < 8; ++f8) {
      f32x4 v = o[f8] * inv;
      *(f32x4*)&orow[f8 * 16 + grp * 4] = v;
    }
  }
}

// ---------------------------------------------------------------- launch

extern "C" void kernel_launch(void* const* d_in, const int* in_sizes, int n_in,
                              void* d_out, int out_size, void* d_ws, size_t ws_size,
                              hipStream_t stream) {
  const float* x  = (const float*)d_in[0];
  const float* Wq = (const float*)d_in[1];
  const float* bq = (const float*)d_in[2];
  const float* Wk = (const float*)d_in[3];
  const float* bk = (const float*)d_in[4];
  const float* Wv = (const float*)d_in[5];
  const float* bv = (const float*)d_in[6];
  float* out = (float*)d_out;

  char* ws = (char*)d_ws;
  short* xb = (short*)ws;                                         // 16 MB
  short* wt = (short*)(ws + (size_t)16 * 1024 * 1024);            // 12 MB
  float* bc = (float*)(ws + (size_t)28 * 1024 * 1024);            // 16 KB slot
  short* qb = (short*)(ws + (size_t)28 * 1024 * 1024 + 65536);    // 16 MB
  short* kb = (short*)((char*)qb + (size_t)16 * 1024 * 1024);     // 4 MB
  short* vt = (short*)((char*)kb + (size_t)4 * 1024 * 1024);      // 4 MB

  conv_x<<<8192, 256, 0, stream>>>((const float4*)x, (s16x4*)xb);
  dim3 tb(32, 8);
  transpose_w<<<dim3(64, 4, 16), tb, 0, stream>>>(Wq, wt, 0);
  transpose_w<<<dim3(64, 4, 4),  tb, 0, stream>>>(Wk, wt, 2048);
  transpose_w<<<dim3(64, 4, 4),  tb, 0, stream>>>(Wv, wt, 2560);
  build_bias<<<12, 256, 0, stream>>>(bq, bk, bv, bc);
  qkv_gemm<<<768, 256, 0, stream>>>(xb, wt, bc, qb, kb, vt);

  (void)hipFuncSetAttribute((const void*)attn, hipFuncAttributeMaxDynamicSharedMemorySize, 65536);
  attn<<<512, 256, 65536, stream>>>(qb, kb, vt, out);
}